// Round 9
// baseline (381.473 us; speedup 1.0000x reference)
//
#include <hip/hip_runtime.h>

#define T_TOK 16
#define K_TOP 8
#define NEXP  64
#define DHID  2048
#define FINT  1024

typedef unsigned int   uint_t;
typedef unsigned short ushort_t;
typedef float f32x4 __attribute__((ext_vector_type(4)));

// workspace layout (bytes)
#define ROUTE_OFF  0u         // 64*16 fp32 = 4 KB
#define AIDX_OFF   4096u      // 64 int
#define NA_OFF     4352u      // 1 int
#define WCTR_OFF   4356u      // 1 int (work counter)
#define UPDONE_OFF 4608u      // 64 int
#define PAIRC_OFF  4864u      // 256 int
#define XTBF_OFF   8192u      // 2048*16 bf16 = 64 KB
#define HPAIR_OFF  131072u    // 256 slots * 8 KB = 2 MB
#define ABUF_OFF   4194304u   // 64*1024*16 bf16 = 2 MB
#define OPART_OFF  8388608u   // 64*16*2048 bf16 = 4 MB

__device__ __forceinline__ ushort_t f2bf(float f) {
    uint_t u = __builtin_bit_cast(uint_t, f);
    u += 0x7FFFu + ((u >> 16) & 1u);   // RNE
    return (ushort_t)(u >> 16);
}
__device__ __forceinline__ uint_t pk2(float lo, float hi) {
    return (uint_t)f2bf(lo) | ((uint_t)f2bf(hi) << 16);
}
__device__ __forceinline__ float bf_lo(uint_t v) { return __builtin_bit_cast(float, v << 16); }
__device__ __forceinline__ float bf_hi(uint_t v) { return __builtin_bit_cast(float, v & 0xFFFF0000u); }
__device__ __forceinline__ float bfround(float f) { return __builtin_bit_cast(float, (uint_t)f2bf(f) << 16); }

// ---------------------------------------------------------------------------
// K1: xt_bf [d][t] bf16-packed (all 32 blocks) + route/aidx/nA + control
// resets (block 0). Runs every call so graph replays start clean.
// ---------------------------------------------------------------------------
__global__ void k_prep(const float* __restrict__ x, const int* __restrict__ idx,
                       const float* __restrict__ w, uint_t* __restrict__ xt_bf,
                       float* __restrict__ route, int* __restrict__ aidx,
                       int* __restrict__ nA, int* __restrict__ wctr,
                       int* __restrict__ up_done, int* __restrict__ pairc) {
    const int tid = threadIdx.x;                 // 256
    const int d = blockIdx.x * 64 + (tid & 63);
    const int tq = tid >> 6;
    float4 v;
    v.x = x[(tq * 4 + 0) * DHID + d];
    v.y = x[(tq * 4 + 1) * DHID + d];
    v.z = x[(tq * 4 + 2) * DHID + d];
    v.w = x[(tq * 4 + 3) * DHID + d];
    *reinterpret_cast<uint2*>(xt_bf + d * 8 + tq * 2) =
        make_uint2(pk2(v.x, v.y), pk2(v.z, v.w));

    if (blockIdx.x != 0) return;
    // control resets
    pairc[tid] = 0;
    if (tid < 64) up_done[tid] = 0;
    if (tid == 0) *wctr = 0;

    __shared__ float r[NEXP * T_TOK];
    __shared__ int is64_s;
    if (tid == 0) {
        int allz = 1;
        for (int i = 1; i < 128; i += 2) allz &= (idx[i] == 0);
        is64_s = allz;
    }
    __syncthreads();
    const int is64 = is64_s;
    for (int i = tid; i < NEXP * T_TOK; i += 256) {
        const int e = i >> 4, t = i & 15;
        float s = 0.f;
#pragma unroll
        for (int k = 0; k < K_TOP; ++k) {
            const int flat = t * K_TOP + k;
            const int ev = is64 ? idx[2 * flat] : idx[flat];
            if (ev == e) s += w[flat];
        }
        r[i] = s;
        route[i] = s;
    }
    __syncthreads();
    if (tid == 0) {
        int n = 0;
        for (int e = 0; e < NEXP; ++e) {
            float s = 0.f;
            for (int t = 0; t < T_TOK; ++t) s += r[e * T_TOK + t];
            if (s != 0.f) aidx[n++] = e;
        }
        *nA = n;
    }
}

// ---- inner-loop machinery --------------------------------------------------
#define FMA4(t, xs)                              \
    acc0[t] = fmaf((xs), w4.x, acc0[t]);         \
    acc1[t] = fmaf((xs), w4.y, acc1[t]);         \
    acc2[t] = fmaf((xs), w4.z, acc2[t]);         \
    acc3[t] = fmaf((xs), w4.w, acc3[t]);
#define FMA_PAIR(u, t0_)                                        \
    { const float xl = bf_lo(u), xh = bf_hi(u);                 \
      FMA4(t0_, xl) FMA4((t0_) + 1, xh) }
#define STEP(jj, B)                                                         \
    { const uint4 q0 = xqw[(jj) * 2]; const uint4 q1 = xqw[(jj) * 2 + 1];   \
      const f32x4 w4 = (B);                                                 \
      FMA_PAIR(q0.x, 0) FMA_PAIR(q0.y, 2) FMA_PAIR(q0.z, 4) FMA_PAIR(q0.w, 6) \
      FMA_PAIR(q1.x, 8) FMA_PAIR(q1.y, 10) FMA_PAIR(q1.z, 12) FMA_PAIR(q1.w, 14) }
#define LDW(j) __builtin_nontemporal_load(wrow + (size_t)(j) * WSTEP)
#define STREAM64()                                                 \
    { f32x4 b0 = LDW(0), b1 = LDW(1), b2 = LDW(2), b3 = LDW(3);    \
      for (int j = 0; j < 64; j += 4) {                            \
          const bool pf = (j < 60);                                \
          STEP(j + 0, b0) if (pf) b0 = LDW(j + 4);                 \
          STEP(j + 1, b1) if (pf) b1 = LDW(j + 5);                 \
          STEP(j + 2, b2) if (pf) b2 = LDW(j + 6);                 \
          STEP(j + 3, b3) if (pf) b3 = LDW(j + 7); } }

// bf16 region = 2048 uints (8 KB): [j(4)][tp(8)][lane(64)]
#define RW_BODY(p)                                                      \
    { _Pragma("unroll") for (int tp = 0; tp < 8; ++tp) {                \
          (p)[(0 * 8 + tp) * 64] = pk2(acc0[2 * tp], acc0[2 * tp + 1]); \
          (p)[(1 * 8 + tp) * 64] = pk2(acc1[2 * tp], acc1[2 * tp + 1]); \
          (p)[(2 * 8 + tp) * 64] = pk2(acc2[2 * tp], acc2[2 * tp + 1]); \
          (p)[(3 * 8 + tp) * 64] = pk2(acc3[2 * tp], acc3[2 * tp + 1]); } }
#define RR_BODY(p)                                                      \
    { _Pragma("unroll") for (int tp = 0; tp < 8; ++tp) {                \
          uint_t u;                                                     \
          u = (p)[(0 * 8 + tp) * 64]; acc0[2 * tp] += bf_lo(u); acc0[2 * tp + 1] += bf_hi(u); \
          u = (p)[(1 * 8 + tp) * 64]; acc1[2 * tp] += bf_lo(u); acc1[2 * tp + 1] += bf_hi(u); \
          u = (p)[(2 * 8 + tp) * 64]; acc2[2 * tp] += bf_lo(u); acc2[2 * tp + 1] += bf_hi(u); \
          u = (p)[(3 * 8 + tp) * 64]; acc3[2 * tp] += bf_lo(u); acc3[2 * tp + 1] += bf_hi(u); } }
#define RW(reg) { uint_t* p_ = lds_u + (reg) * 2048 + lane; RW_BODY(p_) }
#define RR(reg) { const uint_t* p_ = lds_u + (reg) * 2048 + lane; RR_BODY(p_) }

// 16-wave -> wave0 tree reduction (regions 0..7 = full 64 KB LDS)
#define TREE16()                                   \
    __syncthreads();                               \
    if (wid >= 8) RW(wid - 8)                      \
    __syncthreads();                               \
    if (wid < 8) RR(wid)                           \
    __syncthreads();                               \
    if (wid >= 4 && wid < 8) RW(wid - 4)           \
    __syncthreads();                               \
    if (wid < 4) RR(wid)                           \
    __syncthreads();                               \
    if (wid >= 2 && wid < 4) RW(wid - 2)           \
    __syncthreads();                               \
    if (wid < 2) RR(wid)                           \
    __syncthreads();                               \
    if (wid == 1) RW(0)                            \
    __syncthreads();

// ---------------------------------------------------------------------------
// K2: persistent fused up+down. 256 blocks x 1024 threads, atomic work list:
// items [0, 8nA)  = up   (ei, fq in 4, dh in 2): 1 MB Wu slab; the two dh
//                   halves pair-combine via a bf16 global partial (both
//                   halves bf16-rounded -> order-independent sum); the 2nd
//                   finisher applies relu^2*route -> a_buf, bumps up_done.
// items [8nA,16nA)= down (ei, dc in 8): waits up_done[ei]==4, streams 1 MB
//                   Wd column slab, writes out_part[e][t][dslice] (bf16).
// Protocol atomics lane-0-predicated + wave-broadcast. Staging = 32 KB
// (2048 uint4 -> TWO stores per thread; this was the R7/R8 bug).
// ---------------------------------------------------------------------------
__global__ __launch_bounds__(1024, 4) void k_fused(
    const uint_t* __restrict__ xt_bf, const float* __restrict__ Wu,
    const float* __restrict__ Wd, const float* __restrict__ route,
    const int* __restrict__ aidx, const int* __restrict__ nAp,
    int* wctr, int* up_done, int* pairc,
    uint_t* hpair, ushort_t* a_buf, ushort_t* out_part) {

    const int tid = threadIdx.x;
    const int wid = tid >> 6, lane = tid & 63;

    __shared__ __align__(16) uint_t lds_u[16384];  // 64 KB
    __shared__ int s_item, s_nitems;

    if (tid == 0) s_nitems = 16 * (*nAp);
    __syncthreads();
    const int nitems = s_nitems;
    const int upN = nitems >> 1;

    for (;;) {
        if (tid == 0)
            s_item = __hip_atomic_fetch_add(wctr, 1, __ATOMIC_RELAXED, __HIP_MEMORY_SCOPE_AGENT);
        __syncthreads();
        const int item = s_item;
        if (item >= nitems) break;

        if (item < upN) {
            // ---------------- up item ----------------
            const int ei = item >> 3;
            const int fq = (item >> 1) & 3;
            const int dh = item & 1;
            const int e = aidx[ei];
            {   // stage x bf16 rows [dh*1024, +1024): 32 KB = 2048 uint4
                const uint4* src = reinterpret_cast<const uint4*>(xt_bf) + (size_t)dh * 2048;
                uint4* dst = reinterpret_cast<uint4*>(lds_u);
                dst[tid] = src[tid];
                dst[tid + 1024] = src[tid + 1024];
            }
            __syncthreads();
            float acc0[16] = {}, acc1[16] = {}, acc2[16] = {}, acc3[16] = {};
            const f32x4* wrow = reinterpret_cast<const f32x4*>(
                Wu + (size_t)e * ((size_t)DHID * FINT)
                   + (size_t)(dh * 1024 + wid * 64) * FINT + fq * 256 + lane * 4);
            const size_t WSTEP = FINT / 4;
            const uint4* xqw = reinterpret_cast<const uint4*>(lds_u) + (size_t)wid * 128;
            STREAM64()
            TREE16()
            if (wid == 0) {
                RR(0)
                const int slot = ei * 4 + fq;
                uint_t* hp = hpair + (size_t)slot * 2048;
                int r = 0;
                if (lane == 0)
                    r = __hip_atomic_fetch_add(pairc + slot, 1, __ATOMIC_ACQ_REL,
                                               __HIP_MEMORY_SCOPE_AGENT);
                r = __shfl(r, 0);
                if (r == 0) {
                    // first finisher: publish bf16 partial
                    { uint_t* p_ = hp + lane; RW_BODY(p_) }
                    __threadfence();
                    if (lane == 0)
                        __hip_atomic_fetch_add(pairc + slot, 1, __ATOMIC_RELEASE,
                                               __HIP_MEMORY_SCOPE_AGENT);
                } else {
                    // second finisher: all lanes acquire-spin, then combine
                    while (__hip_atomic_load(pairc + slot, __ATOMIC_ACQUIRE,
                                             __HIP_MEMORY_SCOPE_AGENT) < 3)
                        __builtin_amdgcn_s_sleep(1);
                    // round own half to bf16 so the combine is role-symmetric
#pragma unroll
                    for (int t = 0; t < 16; ++t) {
                        acc0[t] = bfround(acc0[t]); acc1[t] = bfround(acc1[t]);
                        acc2[t] = bfround(acc2[t]); acc3[t] = bfround(acc3[t]);
                    }
                    { const uint_t* p_ = hp + lane; RR_BODY(p_) }
                    float rt[16];
#pragma unroll
                    for (int t = 0; t < 16; ++t) rt[t] = route[e * T_TOK + t];
#define ACT(A, t) (rt[t] * fmaxf(A[t], 0.f) * fmaxf(A[t], 0.f))
                    uint4* ap = reinterpret_cast<uint4*>(
                        a_buf + ((size_t)e * FINT + fq * 256 + lane * 4) * T_TOK);
                    uint4 o;
#define ST_COL(A, k0)                                                            \
                    o.x = pk2(ACT(A, 0), ACT(A, 1));   o.y = pk2(ACT(A, 2), ACT(A, 3));   \
                    o.z = pk2(ACT(A, 4), ACT(A, 5));   o.w = pk2(ACT(A, 6), ACT(A, 7));   \
                    ap[k0] = o;                                                           \
                    o.x = pk2(ACT(A, 8), ACT(A, 9));   o.y = pk2(ACT(A, 10), ACT(A, 11)); \
                    o.z = pk2(ACT(A, 12), ACT(A, 13)); o.w = pk2(ACT(A, 14), ACT(A, 15)); \
                    ap[k0 + 1] = o;
                    ST_COL(acc0, 0) ST_COL(acc1, 2) ST_COL(acc2, 4) ST_COL(acc3, 6)
#undef ST_COL
#undef ACT
                    __threadfence();
                    if (lane == 0)
                        __hip_atomic_fetch_add(up_done + ei, 1, __ATOMIC_RELEASE,
                                               __HIP_MEMORY_SCOPE_AGENT);
                }
            }
        } else {
            // ---------------- down item ----------------
            const int it2 = item - upN;
            const int ei = it2 >> 3;
            const int dc = it2 & 7;
            const int e = aidx[ei];
            if (tid == 0) {
                while (__hip_atomic_load(up_done + ei, __ATOMIC_ACQUIRE,
                                         __HIP_MEMORY_SCOPE_AGENT) < 4)
                    __builtin_amdgcn_s_sleep(2);
            }
            __syncthreads();  // extends tid0's acquire happens-before to the block
            {   // stage a[e] bf16: 32 KB = 2048 uint4
                const uint4* src = reinterpret_cast<const uint4*>(
                    a_buf + (size_t)e * FINT * T_TOK);
                uint4* dst = reinterpret_cast<uint4*>(lds_u);
                dst[tid] = src[tid];
                dst[tid + 1024] = src[tid + 1024];
            }
            __syncthreads();
            float acc0[16] = {}, acc1[16] = {}, acc2[16] = {}, acc3[16] = {};
            const f32x4* wrow = reinterpret_cast<const f32x4*>(
                Wd + (size_t)e * ((size_t)FINT * DHID)
                   + (size_t)(wid * 64) * DHID + dc * 256 + lane * 4);
            const size_t WSTEP = DHID / 4;
            const uint4* xqw = reinterpret_cast<const uint4*>(lds_u) + (size_t)wid * 128;
            STREAM64()
            TREE16()
            if (wid == 0) {
                RR(0)
                ushort_t* op = out_part + (size_t)e * (T_TOK * DHID) + dc * 256 + lane * 4;
#pragma unroll
                for (int t = 0; t < 16; ++t) {
                    uint2 u;
                    u.x = pk2(acc0[t], acc1[t]);
                    u.y = pk2(acc2[t], acc3[t]);
                    *reinterpret_cast<uint2*>(op + (size_t)t * DHID) = u;
                }
            }
        }
        __syncthreads();
    }
}

// ---------------------------------------------------------------------------
// K3: out[t][d] = sum over active e of out_part[e][t][d]. Overwrites d_out.
// ---------------------------------------------------------------------------
__global__ void k_comb(const ushort_t* __restrict__ out_part, const int* __restrict__ aidx,
                       const int* __restrict__ nAp, float* __restrict__ out) {
    const int i = blockIdx.x * 256 + threadIdx.x;  // [0, T*D/4)
    const int nA = *nAp;
    const int t = i >> 9;
    const int d = (i & 511) * 4;
    const size_t off = (size_t)t * DHID + d;
    float s0 = 0.f, s1 = 0.f, s2 = 0.f, s3 = 0.f;
    for (int a = 0; a < nA; ++a) {
        const uint2 v = *reinterpret_cast<const uint2*>(
            out_part + (size_t)aidx[a] * (T_TOK * DHID) + off);
        s0 += bf_lo(v.x); s1 += bf_hi(v.x);
        s2 += bf_lo(v.y); s3 += bf_hi(v.y);
    }
    *reinterpret_cast<float4*>(out + off) = make_float4(s0, s1, s2, s3);
}

// ---------------------------------------------------------------------------
extern "C" void kernel_launch(void* const* d_in, const int* in_sizes, int n_in,
                              void* d_out, int out_size, void* d_ws, size_t ws_size,
                              hipStream_t stream) {
    (void)in_sizes; (void)n_in; (void)out_size; (void)ws_size;
    const float* x   = (const float*)d_in[0];
    const int*   idx = (const int*)d_in[1];
    const float* w   = (const float*)d_in[2];
    const float* Wu  = (const float*)d_in[3];
    const float* Wd  = (const float*)d_in[4];
    float* out = (float*)d_out;

    char* ws = (char*)d_ws;
    float*    route    = (float*)(ws + ROUTE_OFF);
    int*      aidx     = (int*)(ws + AIDX_OFF);
    int*      nA       = (int*)(ws + NA_OFF);
    int*      wctr     = (int*)(ws + WCTR_OFF);
    int*      up_done  = (int*)(ws + UPDONE_OFF);
    int*      pairc    = (int*)(ws + PAIRC_OFF);
    uint_t*   xt_bf    = (uint_t*)(ws + XTBF_OFF);
    uint_t*   hpair    = (uint_t*)(ws + HPAIR_OFF);
    ushort_t* a_buf    = (ushort_t*)(ws + ABUF_OFF);
    ushort_t* out_part = (ushort_t*)(ws + OPART_OFF);

    k_prep<<<DHID / 64, 256, 0, stream>>>(x, idx, w, xt_bf, route, aidx, nA,
                                          wctr, up_done, pairc);
    k_fused<<<256, 1024, 0, stream>>>(xt_bf, Wu, Wd, route, aidx, nA,
                                      wctr, up_done, pairc, hpair, a_buf, out_part);
    k_comb<<<(T_TOK * DHID / 4) / 256, 256, 0, stream>>>(out_part, aidx, nA, out);
}

// Round 10
// 270.763 us; speedup vs baseline: 1.4089x; 1.4089x over previous
//
#include <hip/hip_runtime.h>

#define T_TOK 16
#define K_TOP 8
#define NEXP  64
#define DHID  2048
#define FINT  1024

typedef unsigned int   uint_t;
typedef unsigned short ushort_t;
typedef float f32x4 __attribute__((ext_vector_type(4)));

// workspace layout (bytes)
#define ROUTE_OFF 0u          // 64*16 fp32 = 4 KB
#define AIDX_OFF  4096u       // 64 int
#define NA_OFF    4352u       // 1 int
#define XTBF_OFF  8192u       // 2048*16 bf16 = 64 KB
#define OPART_OFF 131072u     // 256 slots * 16*2048 bf16 = 16 MB

__device__ __forceinline__ ushort_t f2bf(float f) {
    uint_t u = __builtin_bit_cast(uint_t, f);
    u += 0x7FFFu + ((u >> 16) & 1u);   // RNE
    return (ushort_t)(u >> 16);
}
__device__ __forceinline__ uint_t pk2(float lo, float hi) {
    return (uint_t)f2bf(lo) | ((uint_t)f2bf(hi) << 16);
}
__device__ __forceinline__ float bf_lo(uint_t v) { return __builtin_bit_cast(float, v << 16); }
__device__ __forceinline__ float bf_hi(uint_t v) { return __builtin_bit_cast(float, v & 0xFFFF0000u); }

// ---------------------------------------------------------------------------
// K1: xt_bf [d][t] bf16-packed (all 32 blocks) + route/aidx/nA (block 0).
// ---------------------------------------------------------------------------
__global__ void k_prep(const float* __restrict__ x, const int* __restrict__ idx,
                       const float* __restrict__ w, uint_t* __restrict__ xt_bf,
                       float* __restrict__ route, int* __restrict__ aidx,
                       int* __restrict__ nA) {
    const int tid = threadIdx.x;                 // 256
    const int d = blockIdx.x * 64 + (tid & 63);
    const int tq = tid >> 6;
    float4 v;
    v.x = x[(tq * 4 + 0) * DHID + d];
    v.y = x[(tq * 4 + 1) * DHID + d];
    v.z = x[(tq * 4 + 2) * DHID + d];
    v.w = x[(tq * 4 + 3) * DHID + d];
    *reinterpret_cast<uint2*>(xt_bf + d * 8 + tq * 2) =
        make_uint2(pk2(v.x, v.y), pk2(v.z, v.w));

    if (blockIdx.x != 0) return;
    __shared__ float r[NEXP * T_TOK];
    __shared__ int is64_s;
    if (tid == 0) {
        int allz = 1;
        for (int i = 1; i < 128; i += 2) allz &= (idx[i] == 0);
        is64_s = allz;
    }
    __syncthreads();
    const int is64 = is64_s;
    for (int i = tid; i < NEXP * T_TOK; i += 256) {
        const int e = i >> 4, t = i & 15;
        float s = 0.f;
#pragma unroll
        for (int k = 0; k < K_TOP; ++k) {
            const int flat = t * K_TOP + k;
            const int ev = is64 ? idx[2 * flat] : idx[flat];
            if (ev == e) s += w[flat];
        }
        r[i] = s;
        route[i] = s;
    }
    __syncthreads();
    if (tid == 0) {
        int n = 0;
        for (int e = 0; e < NEXP; ++e) {
            float s = 0.f;
            for (int t = 0; t < T_TOK; ++t) s += r[e * T_TOK + t];
            if (s != 0.f) aidx[n++] = e;
        }
        *nA = n;
    }
}

// ---- inner-loop machinery --------------------------------------------------
#define FMA4(t, xs)                              \
    acc0[t] = fmaf((xs), w4.x, acc0[t]);         \
    acc1[t] = fmaf((xs), w4.y, acc1[t]);         \
    acc2[t] = fmaf((xs), w4.z, acc2[t]);         \
    acc3[t] = fmaf((xs), w4.w, acc3[t]);
#define FMA_PAIR(u, t0_)                                        \
    { const float xl = bf_lo(u), xh = bf_hi(u);                 \
      FMA4(t0_, xl) FMA4((t0_) + 1, xh) }
#define STEP(jj, B)                                                         \
    { const uint4 q0 = xqw[(jj) * 2]; const uint4 q1 = xqw[(jj) * 2 + 1];   \
      const f32x4 w4 = (B);                                                 \
      FMA_PAIR(q0.x, 0) FMA_PAIR(q0.y, 2) FMA_PAIR(q0.z, 4) FMA_PAIR(q0.w, 6) \
      FMA_PAIR(q1.x, 8) FMA_PAIR(q1.y, 10) FMA_PAIR(q1.z, 12) FMA_PAIR(q1.w, 14) }
#define LDW(j) __builtin_nontemporal_load(wrow + (size_t)(j) * WSTEP)
#define STREAM128()                                                \
    { f32x4 b0 = LDW(0), b1 = LDW(1), b2 = LDW(2), b3 = LDW(3);    \
      for (int j = 0; j < 128; j += 4) {                           \
          const bool pf = (j < 124);                               \
          STEP(j + 0, b0) if (pf) b0 = LDW(j + 4);                 \
          STEP(j + 1, b1) if (pf) b1 = LDW(j + 5);                 \
          STEP(j + 2, b2) if (pf) b2 = LDW(j + 6);                 \
          STEP(j + 3, b3) if (pf) b3 = LDW(j + 7); } }

// bf16 region = 2048 uints (8 KB): [j(4)][tp(8)][lane(64)]
#define RW(reg)                                                         \
    { uint_t* p = lds_u + (reg) * 2048 + lane;                          \
      _Pragma("unroll") for (int tp = 0; tp < 8; ++tp) {                \
          p[(0 * 8 + tp) * 64] = pk2(acc0[2 * tp], acc0[2 * tp + 1]);   \
          p[(1 * 8 + tp) * 64] = pk2(acc1[2 * tp], acc1[2 * tp + 1]);   \
          p[(2 * 8 + tp) * 64] = pk2(acc2[2 * tp], acc2[2 * tp + 1]);   \
          p[(3 * 8 + tp) * 64] = pk2(acc3[2 * tp], acc3[2 * tp + 1]); } }
#define RR(reg)                                                         \
    { const uint_t* p = lds_u + (reg) * 2048 + lane;                    \
      _Pragma("unroll") for (int tp = 0; tp < 8; ++tp) {                \
          uint_t u;                                                     \
          u = p[(0 * 8 + tp) * 64]; acc0[2 * tp] += bf_lo(u); acc0[2 * tp + 1] += bf_hi(u); \
          u = p[(1 * 8 + tp) * 64]; acc1[2 * tp] += bf_lo(u); acc1[2 * tp + 1] += bf_hi(u); \
          u = p[(2 * 8 + tp) * 64]; acc2[2 * tp] += bf_lo(u); acc2[2 * tp + 1] += bf_hi(u); \
          u = p[(3 * 8 + tp) * 64]; acc3[2 * tp] += bf_lo(u); acc3[2 * tp + 1] += bf_hi(u); } }

// 16-wave -> wave0 tree reduction (regions 0..7 = full 64 KB LDS)
#define TREE16()                                   \
    __syncthreads();                               \
    if (wid >= 8) RW(wid - 8)                      \
    __syncthreads();                               \
    if (wid < 8) RR(wid)                           \
    __syncthreads();                               \
    if (wid >= 4 && wid < 8) RW(wid - 4)           \
    __syncthreads();                               \
    if (wid < 4) RR(wid)                           \
    __syncthreads();                               \
    if (wid >= 2 && wid < 4) RW(wid - 2)           \
    __syncthreads();                               \
    if (wid < 2) RR(wid)                           \
    __syncthreads();                               \
    if (wid == 1) RW(0)                            \
    __syncthreads();

// ---------------------------------------------------------------------------
// K2: fused per-(expert, f-quarter) pipeline. Block b = ei*4 + q.
// Phase A (up): 16 waves stream Wu[e][:, q*256 +lane*4] (2 MB, 128 d-rows per
//   wave) against x (staged bf16, 64 KB LDS); TREE16 -> wave0 applies
//   relu^2*route -> a-quarter bf16 into 8 KB LDS. NO global round trip.
// Phase B (down): waves (fs=wid>>3, dq=wid&7) stream Wd[e][q*256+fs*128 ..][:]
//   (2 MB slab) against the LDS a-quarter; 2->1 fs-combine; write bf16
//   out_part[b][t][dq*256 + lane*4]. Zero inter-block communication.
// ---------------------------------------------------------------------------
__global__ __launch_bounds__(1024, 4) void k_main(
    const uint_t* __restrict__ xt_bf, const float* __restrict__ Wu,
    const float* __restrict__ Wd, const float* __restrict__ route,
    const int* __restrict__ aidx, const int* __restrict__ nAp,
    ushort_t* __restrict__ out_part) {
    const int b = blockIdx.x;
    if (b >= 4 * (*nAp)) return;
    const int e = aidx[b >> 2];
    const int q = b & 3;
    const int tid = threadIdx.x;
    const int wid = tid >> 6, lane = tid & 63;

    __shared__ __align__(16) uint_t lds_u[16384];  // 64 KB: x stage / trees
    __shared__ __align__(16) uint_t a_lds[2048];   // 8 KB: a-quarter [f(256)][tp(8)]

    {   // stage full x bf16: 64 KB = 4096 uint4, FOUR stores per thread
        const uint4* src = reinterpret_cast<const uint4*>(xt_bf);
        uint4* dst = reinterpret_cast<uint4*>(lds_u);
        dst[tid] = src[tid];
        dst[tid + 1024] = src[tid + 1024];
        dst[tid + 2048] = src[tid + 2048];
        dst[tid + 3072] = src[tid + 3072];
    }
    __syncthreads();

    float acc0[16] = {}, acc1[16] = {}, acc2[16] = {}, acc3[16] = {};

    // ---------------- phase A: up-proj quarter ----------------
    {
        const f32x4* wrow = reinterpret_cast<const f32x4*>(
            Wu + (size_t)e * ((size_t)DHID * FINT)
               + (size_t)(wid * 128) * FINT + q * 256 + lane * 4);
        const size_t WSTEP = FINT / 4;
        const uint4* xqw = reinterpret_cast<const uint4*>(lds_u) + (size_t)wid * 256;
        STREAM128()
    }
    TREE16()
    if (wid == 0) {
        RR(0)
        float rt[16];
#pragma unroll
        for (int t = 0; t < 16; ++t) rt[t] = route[e * T_TOK + t];
#define ACT(A, t) (rt[t] * fmaxf(A[t], 0.f) * fmaxf(A[t], 0.f))
        // lane's 4 f-cols: f = lane*4 + j -> uint4 slots lane*8 + j*2, +1
        uint4* ap = reinterpret_cast<uint4*>(a_lds) + (size_t)lane * 8;
        uint4 o;
#define ST_COL(A, j2)                                                            \
        o.x = pk2(ACT(A, 0), ACT(A, 1));   o.y = pk2(ACT(A, 2), ACT(A, 3));      \
        o.z = pk2(ACT(A, 4), ACT(A, 5));   o.w = pk2(ACT(A, 6), ACT(A, 7));      \
        ap[j2] = o;                                                              \
        o.x = pk2(ACT(A, 8), ACT(A, 9));   o.y = pk2(ACT(A, 10), ACT(A, 11));    \
        o.z = pk2(ACT(A, 12), ACT(A, 13)); o.w = pk2(ACT(A, 14), ACT(A, 15));    \
        ap[j2 + 1] = o;
        ST_COL(acc0, 0) ST_COL(acc1, 2) ST_COL(acc2, 4) ST_COL(acc3, 6)
#undef ST_COL
#undef ACT
    }
    __syncthreads();

    // ---------------- phase B: down-proj slab ----------------
#pragma unroll
    for (int t = 0; t < 16; ++t) { acc0[t] = 0.f; acc1[t] = 0.f; acc2[t] = 0.f; acc3[t] = 0.f; }
    const int fs = wid >> 3, dq = wid & 7;
    {
        const f32x4* wrow = reinterpret_cast<const f32x4*>(
            Wd + (size_t)e * ((size_t)FINT * DHID)
               + (size_t)(q * 256 + fs * 128) * DHID + dq * 256 + lane * 4);
        const size_t WSTEP = DHID / 4;
        const uint4* xqw = reinterpret_cast<const uint4*>(a_lds) + (size_t)fs * 256;
        STREAM128()
    }
    __syncthreads();
    if (fs == 1) RW(dq)
    __syncthreads();
    if (fs == 0) {
        RR(dq)
        ushort_t* op = out_part + (size_t)b * (T_TOK * DHID) + dq * 256 + lane * 4;
#pragma unroll
        for (int t = 0; t < 16; ++t) {
            uint2 u;
            u.x = pk2(acc0[t], acc1[t]);
            u.y = pk2(acc2[t], acc3[t]);
            *reinterpret_cast<uint2*>(op + (size_t)t * DHID) = u;
        }
    }
}

// ---------------------------------------------------------------------------
// K3: out[t][d] = sum over slots s in [0, 4*nA) of out_part[s][t][d].
// Fully overwrites d_out.
// ---------------------------------------------------------------------------
__global__ void k_comb(const ushort_t* __restrict__ out_part, const int* __restrict__ nAp,
                       float* __restrict__ out) {
    const int i = blockIdx.x * 256 + threadIdx.x;  // [0, T*D/4)
    const int nS = 4 * (*nAp);
    const int t = i >> 9;
    const int d = (i & 511) * 4;
    const size_t off = (size_t)t * DHID + d;
    float s0 = 0.f, s1 = 0.f, s2 = 0.f, s3 = 0.f;
    for (int s = 0; s < nS; ++s) {
        const uint2 v = *reinterpret_cast<const uint2*>(
            out_part + (size_t)s * (T_TOK * DHID) + off);
        s0 += bf_lo(v.x); s1 += bf_hi(v.x);
        s2 += bf_lo(v.y); s3 += bf_hi(v.y);
    }
    *reinterpret_cast<float4*>(out + off) = make_float4(s0, s1, s2, s3);
}

// ---------------------------------------------------------------------------
extern "C" void kernel_launch(void* const* d_in, const int* in_sizes, int n_in,
                              void* d_out, int out_size, void* d_ws, size_t ws_size,
                              hipStream_t stream) {
    (void)in_sizes; (void)n_in; (void)out_size; (void)ws_size;
    const float* x   = (const float*)d_in[0];
    const int*   idx = (const int*)d_in[1];
    const float* w   = (const float*)d_in[2];
    const float* Wu  = (const float*)d_in[3];
    const float* Wd  = (const float*)d_in[4];
    float* out = (float*)d_out;

    char* ws = (char*)d_ws;
    float*    route    = (float*)(ws + ROUTE_OFF);
    int*      aidx     = (int*)(ws + AIDX_OFF);
    int*      nA       = (int*)(ws + NA_OFF);
    uint_t*   xt_bf    = (uint_t*)(ws + XTBF_OFF);
    ushort_t* out_part = (ushort_t*)(ws + OPART_OFF);

    k_prep<<<DHID / 64, 256, 0, stream>>>(x, idx, w, xt_bf, route, aidx, nA);
    k_main<<<4 * NEXP, 1024, 0, stream>>>(xt_bf, Wu, Wd, route, aidx, nA, out_part);
    k_comb<<<(T_TOK * DHID / 4) / 256, 256, 0, stream>>>(out_part, nA, out);
}